// Round 10
// baseline (128.573 us; speedup 1.0000x reference)
//
#include <hip/hip_runtime.h>
#include <hip/hip_bf16.h>
#include <math.h>

typedef short bf16x8 __attribute__((ext_vector_type(8)));
typedef float f32x4 __attribute__((ext_vector_type(4)));

#define T_SEQ 2048
#define C_DIM 1024
#define H_HEADS 16
#define D_HEAD 64
#define BT 4096          // B*T
#define C3 3072
#define BH 32            // B*H

static __device__ inline unsigned short bf_bits(float f) {
    __hip_bfloat16 h = __float2bfloat16(f);
    unsigned short u;
    __builtin_memcpy(&u, &h, 2);
    return u;
}

// packed f32x2 -> bf16x2 (RNE), single instruction
static __device__ inline unsigned int cvtpk(float lo, float hi) {
    unsigned int r;
    asm("v_cvt_pk_bf16_f32 %0, %1, %2" : "=v"(r) : "v"(lo), "v"(hi));
    return r;
}

__device__ __forceinline__ void gload16(const void* g, void* l) {
    __builtin_amdgcn_global_load_lds(
        (const __attribute__((address_space(1))) void*)g,
        (__attribute__((address_space(3))) void*)l, 16, 0, 0);
}

// LDS XOR swizzle (element units, 8-elem granule): spreads rows across bank quads
__device__ __forceinline__ int swz(int r) {
    return ((((r & 3) ^ ((r >> 3) & 3)) | (((r >> 3) & 1) << 2)) << 3);
}

// pipeline barriers: counted vmcnt + raw s_barrier (stage loads stay in flight)
#define PIPE_WAIT_BARRIER(N)                                   \
    asm volatile("s_waitcnt vmcnt(" #N ")" ::: "memory");      \
    __builtin_amdgcn_s_barrier();                              \
    asm volatile("" ::: "memory");                             \
    __builtin_amdgcn_sched_barrier(0)

#define PIPE_END_BARRIER()                                     \
    asm volatile("" ::: "memory");                             \
    __builtin_amdgcn_sched_barrier(0);                         \
    __builtin_amdgcn_s_barrier()

// ---------------- cast f32 -> bf16, 4 elems/thread ----------------
__global__ void cast_f32_bf16(const float* __restrict__ in,
                              __hip_bfloat16* __restrict__ out, int n4) {
    int i = blockIdx.x * blockDim.x + threadIdx.x;
    if (i >= n4) return;
    float4 v = reinterpret_cast<const float4*>(in)[i];
    ushort4 o;
    o.x = bf_bits(v.x); o.y = bf_bits(v.y); o.z = bf_bits(v.z); o.w = bf_bits(v.w);
    reinterpret_cast<ushort4*>(out)[i] = o;
}

// ---------------- GEMM: Cout = A(M,K) * Bw(N,K)^T, bf16 MFMA ----------------
// 128x128 tile, BK=64, 4 waves. Double-buffered global_load_lds pipeline with
// COUNTED vmcnt: stage(t+1) issued before compute(t); barrier waits only for
// stage(t) (vmcnt(8)), so stage(t+1) stays in flight across the compute phase.
// XCD-chunked block swizzle (grid % 8 == 0) for L2 panel locality.
template<int OUT_BF16>
__global__ __launch_bounds__(256) void gemm_bt(
    const __hip_bfloat16* __restrict__ A,
    const __hip_bfloat16* __restrict__ Bw,
    void* __restrict__ Cout, int M, int N, int K) {
    __shared__ __hip_bfloat16 As[2][128][64];
    __shared__ __hip_bfloat16 Bs[2][128][64];
    const int t = threadIdx.x;
    const int lane = t & 63, w = t >> 6;
    const int wr = w >> 1, wc = w & 1;
    const int l15 = lane & 15, lg = lane >> 4;

    // XCD-chunked swizzle (nwg divisible by 8)
    const int gx = gridDim.x;
    const int nwg = gx * gridDim.y;
    const int orig = blockIdx.x + gx * blockIdx.y;
    const int cpx = nwg >> 3;
    const int wg = (orig & 7) * cpx + (orig >> 3);
    const int m0 = (wg / gx) * 128, n0 = (wg % gx) * 128;

    const int srow = lane >> 3;                   // 0..7 (row within 8-row stripe)
    const int scol = ((lane & 7) ^ srow) * 8;     // pre-swizzled global col granule
    const int xr = (l15 & 7) << 3;                // read-side XOR (element units)

    f32x4 acc[4][4];
    f32x4 zero4 = {0.f, 0.f, 0.f, 0.f};
#pragma unroll
    for (int m = 0; m < 4; m++)
#pragma unroll
        for (int n = 0; n < 4; n++) acc[m][n] = zero4;

    auto stage = [&](int buf, int k0) {
#pragma unroll
        for (int i = 0; i < 4; i++) {
            int rbase = w * 32 + i * 8;
            gload16(&A[(size_t)(m0 + rbase + srow) * K + k0 + scol], &As[buf][rbase][0]);
            gload16(&Bw[(size_t)(n0 + rbase + srow) * K + k0 + scol], &Bs[buf][rbase][0]);
        }
    };

    const int nt = K >> 6;
    stage(0, 0);
    int cur = 0;

    for (int tk = 0; tk < nt; tk++) {
        if (tk + 1 < nt) {
            stage(cur ^ 1, (tk + 1) << 6);    // 8 more loads in flight
            PIPE_WAIT_BARRIER(8);             // stage(tk) landed; stage(tk+1) still flying
        } else {
            PIPE_WAIT_BARRIER(0);
        }
#pragma unroll
        for (int kk = 0; kk < 2; kk++) {
            bf16x8 a[4], b[4];
            const int co = (kk * 32 + lg * 8) ^ xr;
#pragma unroll
            for (int m = 0; m < 4; m++)
                a[m] = *reinterpret_cast<const bf16x8*>(&As[cur][wr * 64 + m * 16 + l15][co]);
#pragma unroll
            for (int n = 0; n < 4; n++)
                b[n] = *reinterpret_cast<const bf16x8*>(&Bs[cur][wc * 64 + n * 16 + l15][co]);
            __builtin_amdgcn_s_setprio(1);
#pragma unroll
            for (int m = 0; m < 4; m++)
#pragma unroll
                for (int n = 0; n < 4; n++)
                    acc[m][n] = __builtin_amdgcn_mfma_f32_16x16x32_bf16(a[m], b[n], acc[m][n], 0, 0, 0);
            __builtin_amdgcn_s_setprio(0);
        }
        PIPE_END_BARRIER();     // all waves done reading buf[cur] before next stage overwrites
        cur ^= 1;
    }

#pragma unroll
    for (int m = 0; m < 4; m++)
#pragma unroll
        for (int n = 0; n < 4; n++)
#pragma unroll
            for (int jj = 0; jj < 4; jj++) {
                int row = m0 + wr * 64 + m * 16 + lg * 4 + jj;
                int col = n0 + wc * 64 + n * 16 + l15;
                float v = acc[m][n][jj];
                if (OUT_BF16)
                    ((__hip_bfloat16*)Cout)[(size_t)row * N + col] = __float2bfloat16(v);
                else
                    ((float*)Cout)[(size_t)row * N + col] = v;
            }
}

// ---------------- RoPE for q,k -> (B,H,T,D); q pre-scaled by 0.125*log2(e) ----------------
__global__ void rope_qk(const __hip_bfloat16* __restrict__ qkv,
                        const float* __restrict__ freqs,
                        __hip_bfloat16* __restrict__ q_s,
                        __hip_bfloat16* __restrict__ k_s) {
    int idx = blockIdx.x * 256 + threadIdx.x;   // BT*H*32 threads
    int i = idx & 31;
    int h = (idx >> 5) & 15;
    int bt = idx >> 9;
    int b = bt >> 11;           // T=2048
    int tp = bt & 2047;
    float th = (float)tp * freqs[i];
    float sn = sinf(th), cs = cosf(th);
    size_t qoff = (size_t)bt * C3 + h * 64;
    float q1 = __bfloat162float(qkv[qoff + 2 * i]);
    float q2 = __bfloat162float(qkv[qoff + 2 * i + 1]);
    float k1 = __bfloat162float(qkv[qoff + C_DIM + 2 * i]);
    float k2 = __bfloat162float(qkv[qoff + C_DIM + 2 * i + 1]);
    size_t obase = ((size_t)(b * H_HEADS + h) * T_SEQ + tp) * D_HEAD;
    const float sc = 0.125f * 1.44269504f;      // 1/sqrt(D) * log2(e)
    q_s[obase + i]      = __float2bfloat16((q1 * cs - q2 * sn) * sc);
    q_s[obase + 32 + i] = __float2bfloat16((q1 * sn + q2 * cs) * sc);
    k_s[obase + i]      = __float2bfloat16(k1 * cs - k2 * sn);
    k_s[obase + 32 + i] = __float2bfloat16(k1 * sn + k2 * cs);
}

// ---------------- V transpose: qkv v-part -> v_t (B,H,D,T) ----------------
__global__ __launch_bounds__(256) void transpose_v(const __hip_bfloat16* __restrict__ qkv,
                                                   __hip_bfloat16* __restrict__ v_t) {
    __shared__ __hip_bfloat16 tile[64][72];
    const int bh = blockIdx.y, tt = blockIdx.x;
    const int b = bh >> 4, h = bh & 15;
    const int t = threadIdx.x;
    const int r = t >> 2, c0 = (t & 3) * 16;
    const __hip_bfloat16* src = qkv + (size_t)(b * T_SEQ + tt * 64 + r) * C3 + 2 * C_DIM + h * 64 + c0;
    uint4 v0 = reinterpret_cast<const uint4*>(src)[0];
    uint4 v1 = reinterpret_cast<const uint4*>(src)[1];
    *reinterpret_cast<uint4*>(&tile[r][c0]) = v0;
    *reinterpret_cast<uint4*>(&tile[r][c0 + 8]) = v1;
    __syncthreads();
    const int d = t >> 2;
    ushort out[16];
#pragma unroll
    for (int i = 0; i < 16; i++) {
        __hip_bfloat16 x = tile[c0 + i][d];
        __builtin_memcpy(&out[i], &x, 2);
    }
    __hip_bfloat16* dst = v_t + (size_t)bh * D_HEAD * T_SEQ + (size_t)d * T_SEQ + tt * 64 + c0;
    reinterpret_cast<uint4*>(dst)[0] = *reinterpret_cast<uint4*>(&out[0]);
    reinterpret_cast<uint4*>(dst)[1] = *reinterpret_cast<uint4*>(&out[8]);
}

// ---------------- flash attention ----------------
// Block = (head bh, 64-row q tile); 1024 blocks (4 blocks/CU), LPT order.
// Swapped QK^T, in-register P; K/V^T staged via global_load_lds (pre-swizzled
// source, linear LDS dest), double-buffered with COUNTED vmcnt pipeline;
// defer-max; MFMA-of-ones row-sum; cvt_pk pack; builtin exp2.
__global__ __launch_bounds__(256, 4) void attn_kernel(
    const __hip_bfloat16* __restrict__ q_s,
    const __hip_bfloat16* __restrict__ k_s,
    const __hip_bfloat16* __restrict__ v_t,
    __hip_bfloat16* __restrict__ y) {
    __shared__ ushort Kbuf[2][64 * 64];
    __shared__ ushort Vbuf[2][64 * 64];

    const int bid = blockIdx.x;                 // 1024 blocks
    const int qt = 31 - (bid >> 5);             // LPT: longest first
    const int bh = bid & 31;                    // bh%8 -> head-per-XCD L2 locality
    const int t = threadIdx.x, lane = t & 63, w = t >> 6;
    const int l15 = lane & 15, lg = lane >> 4;
    const size_t hbase = (size_t)bh * T_SEQ * D_HEAD;
    const int qr = qt * 64 + w * 16 + l15;

    // Q fragment
    bf16x8 aq[2];
#pragma unroll
    for (int dd = 0; dd < 2; dd++)
        aq[dd] = *reinterpret_cast<const bf16x8*>(&q_s[hbase + (size_t)qr * 64 + dd * 32 + lg * 8]);

    // ones fragment (bf16 1.0 = 0x3F80) for MFMA row-sum
    bf16x8 ones;
#pragma unroll
    for (int i = 0; i < 8; i++) ones[i] = (short)0x3F80;

    f32x4 zero4 = {0.f, 0.f, 0.f, 0.f};
    f32x4 o[4];
#pragma unroll
    for (int dc = 0; dc < 4; dc++) o[dc] = zero4;
    f32x4 lacc = zero4;          // row-sum accumulator ([0] is the live value)
    float mr = -INFINITY;

    // LDS read offsets (element units), hoisted
    int koff[4][2], voff[4][2];
#pragma unroll
    for (int c = 0; c < 4; c++) {
        int kro = ((c >> 1) << 5) + ((c & 1) << 2) + ((l15 >> 2) << 3) + (l15 & 3);
        int sz = swz(kro);
#pragma unroll
        for (int dd = 0; dd < 2; dd++)
            koff[c][dd] = kro * 64 + ((dd * 32 + lg * 8) ^ sz);
    }
#pragma unroll
    for (int dc = 0; dc < 4; dc++) {
        int vro = dc * 16 + l15;
        int sz = swz(vro);
#pragma unroll
        for (int dd = 0; dd < 2; dd++)
            voff[dc][dd] = vro * 64 + ((dd * 32 + lg * 8) ^ sz);
    }

    // staging geometry: thread t -> tile row r_i = i*32 + (t>>3), granule t&7.
    const int srow = t >> 3;                // 0..31
    const int sgr = t & 7;

    auto stageKV = [&](int buf, int kbase) {
#pragma unroll
        for (int i = 0; i < 2; i++) {
            int r = i * 32 + srow;
            int gsw = (sgr ^ (swz(r) >> 3)) * 8;
            gload16(&k_s[hbase + (size_t)(kbase + r) * 64 + gsw],
                    &Kbuf[buf][(i * 32 + w * 8) * 64]);
            gload16(&v_t[hbase + (size_t)r * T_SEQ + kbase + gsw],
                    &Vbuf[buf][(i * 32 + w * 8) * 64]);
        }
    };

    int cur = 0;
    stageKV(0, 0);

    for (int kt = 0; kt <= qt; kt++) {
        const int kt64 = kt << 6;
        if (kt < qt) {
            stageKV(cur ^ 1, kt64 + 64);    // 4 more loads in flight
            PIPE_WAIT_BARRIER(4);           // stage(kt) landed; stage(kt+1) still flying
        } else {
            PIPE_WAIT_BARRIER(0);
        }

        const ushort* Kc = Kbuf[cur];
        const ushort* Vc = Vbuf[cur];
        bf16x8 kf[4][2], av[4][2];
#pragma unroll
        for (int c = 0; c < 4; c++)
#pragma unroll
            for (int dd = 0; dd < 2; dd++)
                kf[c][dd] = *reinterpret_cast<const bf16x8*>(&Kc[koff[c][dd]]);
#pragma unroll
        for (int dc = 0; dc < 4; dc++)
#pragma unroll
            for (int dd = 0; dd < 2; dd++)
                av[dc][dd] = *reinterpret_cast<const bf16x8*>(&Vc[voff[dc][dd]]);

        // ---- S^T = K * Q^T ----
        f32x4 st[4];
        __builtin_amdgcn_s_setprio(1);
#pragma unroll
        for (int c = 0; c < 4; c++) {
            st[c] = zero4;
#pragma unroll
            for (int dd = 0; dd < 2; dd++)
                st[c] = __builtin_amdgcn_mfma_f32_16x16x32_bf16(kf[c][dd], aq[dd], st[c], 0, 0, 0);
        }
        __builtin_amdgcn_s_setprio(0);

        if (kt == qt) {     // causal mask on diagonal tile
#pragma unroll
            for (int c = 0; c < 4; c++) {
                int kb = kt64 + ((c >> 1) << 5) + ((c & 1) << 2) + lg * 8;
#pragma unroll
                for (int jj = 0; jj < 4; jj++)
                    if (kb + jj > qr) st[c][jj] = -INFINITY;
            }
        }

        // ---- tile max: tree reduction ----
        float m0a = fmaxf(st[0][0], st[0][1]), m0b = fmaxf(st[0][2], st[0][3]);
        float m1a = fmaxf(st[1][0], st[1][1]), m1b = fmaxf(st[1][2], st[1][3]);
        float m2a = fmaxf(st[2][0], st[2][1]), m2b = fmaxf(st[2][2], st[2][3]);
        float m3a = fmaxf(st[3][0], st[3][1]), m3b = fmaxf(st[3][2], st[3][3]);
        float mx = fmaxf(fmaxf(fmaxf(m0a, m0b), fmaxf(m1a, m1b)),
                         fmaxf(fmaxf(m2a, m2b), fmaxf(m3a, m3b)));
        mx = fmaxf(mx, __shfl_xor(mx, 16));
        mx = fmaxf(mx, __shfl_xor(mx, 32));

        // ---- defer-max: rescale only when max grew past THR=8 (log2 domain) ----
        if (__any(mx - mr > 8.f)) {
            float mnew = fmaxf(mr, mx);
            float scl = __builtin_amdgcn_exp2f(mr - mnew);
            mr = mnew;
            lacc[0] *= scl;
#pragma unroll
            for (int dc = 0; dc < 4; dc++)
#pragma unroll
                for (int jj = 0; jj < 4; jj++) o[dc][jj] *= scl;
        }

        // ---- P = exp2(S - mr) (bare v_exp_f32), pack to bf16 (cvt_pk) ----
#pragma unroll
        for (int c = 0; c < 4; c++)
#pragma unroll
            for (int jj = 0; jj < 4; jj++)
                st[c][jj] = __builtin_amdgcn_exp2f(st[c][jj] - mr);

        union { bf16x8 v; unsigned int u[4]; } pf0, pf1;
        pf0.u[0] = cvtpk(st[0][0], st[0][1]);
        pf0.u[1] = cvtpk(st[0][2], st[0][3]);
        pf0.u[2] = cvtpk(st[1][0], st[1][1]);
        pf0.u[3] = cvtpk(st[1][2], st[1][3]);
        pf1.u[0] = cvtpk(st[2][0], st[2][1]);
        pf1.u[1] = cvtpk(st[2][2], st[2][3]);
        pf1.u[2] = cvtpk(st[3][0], st[3][1]);
        pf1.u[3] = cvtpk(st[3][2], st[3][3]);

        // ---- O^T += V^T P ; row-sum via MFMA-of-ones ----
        __builtin_amdgcn_s_setprio(1);
        lacc = __builtin_amdgcn_mfma_f32_16x16x32_bf16(ones, pf0.v, lacc, 0, 0, 0);
        lacc = __builtin_amdgcn_mfma_f32_16x16x32_bf16(ones, pf1.v, lacc, 0, 0, 0);
#pragma unroll
        for (int dc = 0; dc < 4; dc++) {
            o[dc] = __builtin_amdgcn_mfma_f32_16x16x32_bf16(av[dc][0], pf0.v, o[dc], 0, 0, 0);
            o[dc] = __builtin_amdgcn_mfma_f32_16x16x32_bf16(av[dc][1], pf1.v, o[dc], 0, 0, 0);
        }
        __builtin_amdgcn_s_setprio(0);

        PIPE_END_BARRIER();     // all waves done reading buf[cur] before next stage overwrites
        cur ^= 1;
    }

    // epilogue: lane holds o^T[d = dc*16 + lg*4 + jj][q = l15]
    const int b = bh >> 4, h = bh & 15;
    float inv = 1.f / lacc[0];
#pragma unroll
    for (int dc = 0; dc < 4; dc++) {
        ushort4 ov;
        ov.x = bf_bits(o[dc][0] * inv);
        ov.y = bf_bits(o[dc][1] * inv);
        ov.z = bf_bits(o[dc][2] * inv);
        ov.w = bf_bits(o[dc][3] * inv);
        *reinterpret_cast<ushort4*>(
            &y[(size_t)(b * T_SEQ + qr) * C_DIM + h * 64 + dc * 16 + lg * 4]) = ov;
    }
}

// ---------------- LayerNorm over C=1024 (bf16 in, f32 out), one block per row ----------------
__global__ __launch_bounds__(256) void ln_kernel(const __hip_bfloat16* __restrict__ y2,
                                                 const float* __restrict__ wgt,
                                                 const float* __restrict__ bias,
                                                 float* __restrict__ out) {
    const int row = blockIdx.x;
    const int t = threadIdx.x;
    ushort4 u = reinterpret_cast<const ushort4*>(y2 + (size_t)row * C_DIM)[t];
    float4 v;
    v.x = __bfloat162float(*(__hip_bfloat16*)&u.x);
    v.y = __bfloat162float(*(__hip_bfloat16*)&u.y);
    v.z = __bfloat162float(*(__hip_bfloat16*)&u.z);
    v.w = __bfloat162float(*(__hip_bfloat16*)&u.w);
    float s = v.x + v.y + v.z + v.w;
    float s2 = v.x * v.x + v.y * v.y + v.z * v.z + v.w * v.w;
#pragma unroll
    for (int d = 1; d < 64; d <<= 1) {
        s += __shfl_xor(s, d);
        s2 += __shfl_xor(s2, d);
    }
    __shared__ float ps[4], ps2[4];
    const int lane = t & 63, w = t >> 6;
    if (lane == 0) { ps[w] = s; ps2[w] = s2; }
    __syncthreads();
    s = ps[0] + ps[1] + ps[2] + ps[3];
    s2 = ps2[0] + ps2[1] + ps2[2] + ps2[3];
    float mean = s * (1.f / C_DIM);
    float var = s2 * (1.f / C_DIM) - mean * mean;
    float inv = rsqrtf(var + 1e-5f);
    float4 wv = reinterpret_cast<const float4*>(wgt)[t];
    float4 bv = reinterpret_cast<const float4*>(bias)[t];
    float4 ov;
    ov.x = (v.x - mean) * inv * wv.x + bv.x;
    ov.y = (v.y - mean) * inv * wv.y + bv.y;
    ov.z = (v.z - mean) * inv * wv.z + bv.z;
    ov.w = (v.w - mean) * inv * wv.w + bv.w;
    reinterpret_cast<float4*>(out + (size_t)row * C_DIM)[t] = ov;
}

extern "C" void kernel_launch(void* const* d_in, const int* in_sizes, int n_in,
                              void* d_out, int out_size, void* d_ws, size_t ws_size,
                              hipStream_t stream) {
    const float* x      = (const float*)d_in[0];
    const float* freqs  = (const float*)d_in[1];
    const float* W_attn = (const float*)d_in[2];
    const float* W_proj = (const float*)d_in[3];
    const float* lnw    = (const float*)d_in[4];
    const float* lnb    = (const float*)d_in[5];
    float* out = (float*)d_out;
    char* ws = (char*)d_ws;

    __hip_bfloat16* xb   = (__hip_bfloat16*)(ws);                 // 8.4 MB
    __hip_bfloat16* Wab  = (__hip_bfloat16*)(ws + 8388608);       // 6.3 MB
    __hip_bfloat16* Wpb  = (__hip_bfloat16*)(ws + 14680064);      // 2.1 MB
    __hip_bfloat16* qkvb = (__hip_bfloat16*)(ws + 16777216);      // 25.2 MB
    __hip_bfloat16* q_s  = (__hip_bfloat16*)(ws + 41943040);      // 8.4 MB
    __hip_bfloat16* k_s  = (__hip_bfloat16*)(ws + 50331648);      // 8.4 MB
    __hip_bfloat16* v_t  = (__hip_bfloat16*)(ws + 58720256);      // 8.4 MB (B,H,D,T)
    __hip_bfloat16* y_at = (__hip_bfloat16*)(ws + 67108864);      // 8.4 MB
    __hip_bfloat16* y2b  = (__hip_bfloat16*)(ws + 75497472);      // 8.4 MB

    // casts
    cast_f32_bf16<<<(BT * C_DIM / 4) / 256, 256, 0, stream>>>(x, xb, BT * C_DIM / 4);
    cast_f32_bf16<<<(C3 * C_DIM / 4) / 256, 256, 0, stream>>>(W_attn, Wab, C3 * C_DIM / 4);
    cast_f32_bf16<<<(C_DIM * C_DIM / 4) / 256, 256, 0, stream>>>(W_proj, Wpb, C_DIM * C_DIM / 4);

    // qkv = x @ W_attn^T
    gemm_bt<1><<<dim3(C3 / 128, BT / 128), 256, 0, stream>>>(xb, Wab, qkvb, BT, C3, C_DIM);

    // rope q,k + transpose v
    rope_qk<<<(BT * H_HEADS * 32) / 256, 256, 0, stream>>>(qkvb, freqs, q_s, k_s);
    transpose_v<<<dim3(T_SEQ / 64, BH), 256, 0, stream>>>(qkvb, v_t);

    // attention: 1024 blocks (32 q-tiles x 32 heads), LPT order
    attn_kernel<<<1024, 256, 0, stream>>>(q_s, k_s, v_t, y_at);

    // proj (bf16 out for cheap LN read)
    gemm_bt<1><<<dim3(C_DIM / 128, BT / 128), 256, 0, stream>>>(y_at, Wpb, y2b, BT, C_DIM, C_DIM);

    // layernorm
    ln_kernel<<<BT, 256, 0, stream>>>(y2b, lnw, lnb, out);
}

// Round 11
// 125.538 us; speedup vs baseline: 1.0242x; 1.0242x over previous
//
#include <hip/hip_runtime.h>
#include <hip/hip_bf16.h>
#include <math.h>

typedef short bf16x8 __attribute__((ext_vector_type(8)));
typedef float f32x4 __attribute__((ext_vector_type(4)));

#define T_SEQ 2048
#define C_DIM 1024
#define H_HEADS 16
#define D_HEAD 64
#define BT 4096          // B*T
#define C3 3072
#define BH 32            // B*H

static __device__ inline unsigned short bf_bits(float f) {
    __hip_bfloat16 h = __float2bfloat16(f);
    unsigned short u;
    __builtin_memcpy(&u, &h, 2);
    return u;
}

// packed f32x2 -> bf16x2 (RNE), single instruction
static __device__ inline unsigned int cvtpk(float lo, float hi) {
    unsigned int r;
    asm("v_cvt_pk_bf16_f32 %0, %1, %2" : "=v"(r) : "v"(lo), "v"(hi));
    return r;
}

__device__ __forceinline__ void gload16(const void* g, void* l) {
    __builtin_amdgcn_global_load_lds(
        (const __attribute__((address_space(1))) void*)g,
        (__attribute__((address_space(3))) void*)l, 16, 0, 0);
}

// LDS XOR swizzle (element units, 8-elem granule): spreads rows across bank quads
__device__ __forceinline__ int swz(int r) {
    return ((((r & 3) ^ ((r >> 3) & 3)) | (((r >> 3) & 1) << 2)) << 3);
}

// ---------------- cast f32 -> bf16, 4 elems/thread ----------------
__global__ void cast_f32_bf16(const float* __restrict__ in,
                              __hip_bfloat16* __restrict__ out, int n4) {
    int i = blockIdx.x * blockDim.x + threadIdx.x;
    if (i >= n4) return;
    float4 v = reinterpret_cast<const float4*>(in)[i];
    ushort4 o;
    o.x = bf_bits(v.x); o.y = bf_bits(v.y); o.z = bf_bits(v.z); o.w = bf_bits(v.w);
    reinterpret_cast<ushort4*>(out)[i] = o;
}

// ---------------- GEMM: Cout = A(M,K) * Bw(N,K)^T, bf16 MFMA ----------------
// 128x128 tile, BK=64, 4 waves. Double-buffered global_load_lds pipeline
// (issue-early: stage tile t+1 before computing tile t; one barrier/iter).
// LDS dest linear; global source column pre-swizzled; reads XOR the involution.
// (Round-10 counted-vmcnt + XCD swizzle were null/negative at this 2-phase
// structure — regime gate; reverted to the round-9 form.)
template<int OUT_BF16>
__global__ __launch_bounds__(256) void gemm_bt(
    const __hip_bfloat16* __restrict__ A,
    const __hip_bfloat16* __restrict__ Bw,
    void* __restrict__ Cout, int M, int N, int K) {
    __shared__ __hip_bfloat16 As[2][128][64];
    __shared__ __hip_bfloat16 Bs[2][128][64];
    const int t = threadIdx.x;
    const int lane = t & 63, w = t >> 6;
    const int wr = w >> 1, wc = w & 1;
    const int l15 = lane & 15, lg = lane >> 4;
    const int m0 = blockIdx.y * 128, n0 = blockIdx.x * 128;

    const int srow = lane >> 3;                   // 0..7 (row within 8-row stripe)
    const int scol = ((lane & 7) ^ srow) * 8;     // pre-swizzled global col granule
    const int xr = (l15 & 7) << 3;                // read-side XOR (element units)

    f32x4 acc[4][4];
    f32x4 zero4 = {0.f, 0.f, 0.f, 0.f};
#pragma unroll
    for (int m = 0; m < 4; m++)
#pragma unroll
        for (int n = 0; n < 4; n++) acc[m][n] = zero4;

    auto stage = [&](int buf, int k0) {
#pragma unroll
        for (int i = 0; i < 4; i++) {
            int rbase = w * 32 + i * 8;
            gload16(&A[(size_t)(m0 + rbase + srow) * K + k0 + scol], &As[buf][rbase][0]);
            gload16(&Bw[(size_t)(n0 + rbase + srow) * K + k0 + scol], &Bs[buf][rbase][0]);
        }
    };

    const int nt = K >> 6;
    stage(0, 0);
    __syncthreads();        // drains vmcnt(0): buf0 ready

    for (int tk = 0; tk < nt; tk++) {
        const int cur = tk & 1;
        if (tk + 1 < nt) stage(cur ^ 1, (tk + 1) << 6);   // issue-early, overlaps compute
#pragma unroll
        for (int kk = 0; kk < 2; kk++) {
            bf16x8 a[4], b[4];
            const int co = (kk * 32 + lg * 8) ^ xr;
#pragma unroll
            for (int m = 0; m < 4; m++)
                a[m] = *reinterpret_cast<const bf16x8*>(&As[cur][wr * 64 + m * 16 + l15][co]);
#pragma unroll
            for (int n = 0; n < 4; n++)
                b[n] = *reinterpret_cast<const bf16x8*>(&Bs[cur][wc * 64 + n * 16 + l15][co]);
            __builtin_amdgcn_s_setprio(1);
#pragma unroll
            for (int m = 0; m < 4; m++)
#pragma unroll
                for (int n = 0; n < 4; n++)
                    acc[m][n] = __builtin_amdgcn_mfma_f32_16x16x32_bf16(a[m], b[n], acc[m][n], 0, 0, 0);
            __builtin_amdgcn_s_setprio(0);
        }
        __syncthreads();    // stage(t+1) done + all reads of buf[cur] done
    }

#pragma unroll
    for (int m = 0; m < 4; m++)
#pragma unroll
        for (int n = 0; n < 4; n++)
#pragma unroll
            for (int jj = 0; jj < 4; jj++) {
                int row = m0 + wr * 64 + m * 16 + lg * 4 + jj;
                int col = n0 + wc * 64 + n * 16 + l15;
                float v = acc[m][n][jj];
                if (OUT_BF16)
                    ((__hip_bfloat16*)Cout)[(size_t)row * N + col] = __float2bfloat16(v);
                else
                    ((float*)Cout)[(size_t)row * N + col] = v;
            }
}

// ---------------- RoPE for q,k -> (B,H,T,D); q pre-scaled by 0.125*log2(e) ----------------
__global__ void rope_qk(const __hip_bfloat16* __restrict__ qkv,
                        const float* __restrict__ freqs,
                        __hip_bfloat16* __restrict__ q_s,
                        __hip_bfloat16* __restrict__ k_s) {
    int idx = blockIdx.x * 256 + threadIdx.x;   // BT*H*32 threads
    int i = idx & 31;
    int h = (idx >> 5) & 15;
    int bt = idx >> 9;
    int b = bt >> 11;           // T=2048
    int tp = bt & 2047;
    float th = (float)tp * freqs[i];
    float sn = sinf(th), cs = cosf(th);
    size_t qoff = (size_t)bt * C3 + h * 64;
    float q1 = __bfloat162float(qkv[qoff + 2 * i]);
    float q2 = __bfloat162float(qkv[qoff + 2 * i + 1]);
    float k1 = __bfloat162float(qkv[qoff + C_DIM + 2 * i]);
    float k2 = __bfloat162float(qkv[qoff + C_DIM + 2 * i + 1]);
    size_t obase = ((size_t)(b * H_HEADS + h) * T_SEQ + tp) * D_HEAD;
    const float sc = 0.125f * 1.44269504f;      // 1/sqrt(D) * log2(e)
    q_s[obase + i]      = __float2bfloat16((q1 * cs - q2 * sn) * sc);
    q_s[obase + 32 + i] = __float2bfloat16((q1 * sn + q2 * cs) * sc);
    k_s[obase + i]      = __float2bfloat16(k1 * cs - k2 * sn);
    k_s[obase + 32 + i] = __float2bfloat16(k1 * sn + k2 * cs);
}

// ---------------- V transpose: qkv v-part -> v_t (B,H,D,T) ----------------
__global__ __launch_bounds__(256) void transpose_v(const __hip_bfloat16* __restrict__ qkv,
                                                   __hip_bfloat16* __restrict__ v_t) {
    __shared__ __hip_bfloat16 tile[64][72];
    const int bh = blockIdx.y, tt = blockIdx.x;
    const int b = bh >> 4, h = bh & 15;
    const int t = threadIdx.x;
    const int r = t >> 2, c0 = (t & 3) * 16;
    const __hip_bfloat16* src = qkv + (size_t)(b * T_SEQ + tt * 64 + r) * C3 + 2 * C_DIM + h * 64 + c0;
    uint4 v0 = reinterpret_cast<const uint4*>(src)[0];
    uint4 v1 = reinterpret_cast<const uint4*>(src)[1];
    *reinterpret_cast<uint4*>(&tile[r][c0]) = v0;
    *reinterpret_cast<uint4*>(&tile[r][c0 + 8]) = v1;
    __syncthreads();
    const int d = t >> 2;
    ushort out[16];
#pragma unroll
    for (int i = 0; i < 16; i++) {
        __hip_bfloat16 x = tile[c0 + i][d];
        __builtin_memcpy(&out[i], &x, 2);
    }
    __hip_bfloat16* dst = v_t + (size_t)bh * D_HEAD * T_SEQ + (size_t)d * T_SEQ + tt * 64 + c0;
    reinterpret_cast<uint4*>(dst)[0] = *reinterpret_cast<uint4*>(&out[0]);
    reinterpret_cast<uint4*>(dst)[1] = *reinterpret_cast<uint4*>(&out[8]);
}

// ---------------- flash attention ----------------
// Block = (head bh, 64-row q tile); 1024 blocks (4 blocks/CU), LPT order.
// Swapped QK^T, in-register P; K/V^T staged via global_load_lds, double-buffered;
// defer-max with SHFL-FREE fast path (cross-lane row-max only on the rare rescale
// path — removes ~250 cyc of ds_bpermute latency per tile-step); MFMA-of-ones
// row-sum; cvt_pk pack; builtin exp2.
__global__ __launch_bounds__(256, 4) void attn_kernel(
    const __hip_bfloat16* __restrict__ q_s,
    const __hip_bfloat16* __restrict__ k_s,
    const __hip_bfloat16* __restrict__ v_t,
    __hip_bfloat16* __restrict__ y) {
    __shared__ ushort Kbuf[2][64 * 64];
    __shared__ ushort Vbuf[2][64 * 64];

    const int bid = blockIdx.x;                 // 1024 blocks
    const int qt = 31 - (bid >> 5);             // LPT: longest first
    const int bh = bid & 31;                    // bh%8 -> head-per-XCD L2 locality
    const int t = threadIdx.x, lane = t & 63, w = t >> 6;
    const int l15 = lane & 15, lg = lane >> 4;
    const size_t hbase = (size_t)bh * T_SEQ * D_HEAD;
    const int qr = qt * 64 + w * 16 + l15;

    // Q fragment
    bf16x8 aq[2];
#pragma unroll
    for (int dd = 0; dd < 2; dd++)
        aq[dd] = *reinterpret_cast<const bf16x8*>(&q_s[hbase + (size_t)qr * 64 + dd * 32 + lg * 8]);

    // ones fragment (bf16 1.0 = 0x3F80) for MFMA row-sum
    bf16x8 ones;
#pragma unroll
    for (int i = 0; i < 8; i++) ones[i] = (short)0x3F80;

    f32x4 zero4 = {0.f, 0.f, 0.f, 0.f};
    f32x4 o[4];
#pragma unroll
    for (int dc = 0; dc < 4; dc++) o[dc] = zero4;
    f32x4 lacc = zero4;          // row-sum accumulator ([0] is the live value)
    float mr = -INFINITY;

    // LDS read offsets (element units), hoisted
    int koff[4][2], voff[4][2];
#pragma unroll
    for (int c = 0; c < 4; c++) {
        int kro = ((c >> 1) << 5) + ((c & 1) << 2) + ((l15 >> 2) << 3) + (l15 & 3);
        int sz = swz(kro);
#pragma unroll
        for (int dd = 0; dd < 2; dd++)
            koff[c][dd] = kro * 64 + ((dd * 32 + lg * 8) ^ sz);
    }
#pragma unroll
    for (int dc = 0; dc < 4; dc++) {
        int vro = dc * 16 + l15;
        int sz = swz(vro);
#pragma unroll
        for (int dd = 0; dd < 2; dd++)
            voff[dc][dd] = vro * 64 + ((dd * 32 + lg * 8) ^ sz);
    }

    // staging geometry: thread t -> tile row r_i = i*32 + (t>>3), granule t&7.
    const int srow = t >> 3;                // 0..31
    const int sgr = t & 7;

    auto stageKV = [&](int buf, int kbase) {
#pragma unroll
        for (int i = 0; i < 2; i++) {
            int r = i * 32 + srow;
            int gsw = (sgr ^ (swz(r) >> 3)) * 8;
            gload16(&k_s[hbase + (size_t)(kbase + r) * 64 + gsw],
                    &Kbuf[buf][(i * 32 + w * 8) * 64]);
            gload16(&v_t[hbase + (size_t)r * T_SEQ + kbase + gsw],
                    &Vbuf[buf][(i * 32 + w * 8) * 64]);
        }
    };

    int cur = 0;
    stageKV(0, 0);
    __syncthreads();        // drains vmcnt: buf0 ready

    for (int kt = 0; kt <= qt; kt++) {
        const int kt64 = kt << 6;
        if (kt < qt) stageKV(cur ^ 1, kt64 + 64);   // in flight during compute

        const ushort* Kc = Kbuf[cur];
        const ushort* Vc = Vbuf[cur];
        bf16x8 kf[4][2], av[4][2];
#pragma unroll
        for (int c = 0; c < 4; c++)
#pragma unroll
            for (int dd = 0; dd < 2; dd++)
                kf[c][dd] = *reinterpret_cast<const bf16x8*>(&Kc[koff[c][dd]]);
#pragma unroll
        for (int dc = 0; dc < 4; dc++)
#pragma unroll
            for (int dd = 0; dd < 2; dd++)
                av[dc][dd] = *reinterpret_cast<const bf16x8*>(&Vc[voff[dc][dd]]);

        // ---- S^T = K * Q^T ----
        f32x4 st[4];
        __builtin_amdgcn_s_setprio(1);
#pragma unroll
        for (int c = 0; c < 4; c++) {
            st[c] = zero4;
#pragma unroll
            for (int dd = 0; dd < 2; dd++)
                st[c] = __builtin_amdgcn_mfma_f32_16x16x32_bf16(kf[c][dd], aq[dd], st[c], 0, 0, 0);
        }
        __builtin_amdgcn_s_setprio(0);

        if (kt == qt) {     // causal mask on diagonal tile
#pragma unroll
            for (int c = 0; c < 4; c++) {
                int kb = kt64 + ((c >> 1) << 5) + ((c & 1) << 2) + lg * 8;
#pragma unroll
                for (int jj = 0; jj < 4; jj++)
                    if (kb + jj > qr) st[c][jj] = -INFINITY;
            }
        }

        // ---- per-lane LOCAL max (no cross-lane shuffles on the fast path) ----
        float m0a = fmaxf(st[0][0], st[0][1]), m0b = fmaxf(st[0][2], st[0][3]);
        float m1a = fmaxf(st[1][0], st[1][1]), m1b = fmaxf(st[1][2], st[1][3]);
        float m2a = fmaxf(st[2][0], st[2][1]), m2b = fmaxf(st[2][2], st[2][3]);
        float m3a = fmaxf(st[3][0], st[3][1]), m3b = fmaxf(st[3][2], st[3][3]);
        float lmx = fmaxf(fmaxf(fmaxf(m0a, m0b), fmaxf(m1a, m1b)),
                          fmaxf(fmaxf(m2a, m2b), fmaxf(m3a, m3b)));

        // ---- defer-max: rescale only when some lane's local max grew past THR=8.
        // If no lane exceeds, every P value is bounded by 2^8 with the OLD mr —
        // safe for bf16 P and f32 row-sum. Cross-lane max only on this rare path.
        if (__any(lmx - mr > 8.f)) {
            float mx = fmaxf(lmx, __shfl_xor(lmx, 16));
            mx = fmaxf(mx, __shfl_xor(mx, 32));
            float mnew = fmaxf(mr, mx);
            float scl = __builtin_amdgcn_exp2f(mr - mnew);
            mr = mnew;
            lacc[0] *= scl;
#pragma unroll
            for (int dc = 0; dc < 4; dc++)
#pragma unroll
                for (int jj = 0; jj < 4; jj++) o[dc][jj] *= scl;
        }

        // ---- P = exp2(S - mr) (bare v_exp_f32), pack to bf16 (cvt_pk) ----
#pragma unroll
        for (int c = 0; c < 4; c++)
#pragma unroll
            for (int jj = 0; jj < 4; jj++)
                st[c][jj] = __builtin_amdgcn_exp2f(st[c][jj] - mr);

        union { bf16x8 v; unsigned int u[4]; } pf0, pf1;
        pf0.u[0] = cvtpk(st[0][0], st[0][1]);
        pf0.u[1] = cvtpk(st[0][2], st[0][3]);
        pf0.u[2] = cvtpk(st[1][0], st[1][1]);
        pf0.u[3] = cvtpk(st[1][2], st[1][3]);
        pf1.u[0] = cvtpk(st[2][0], st[2][1]);
        pf1.u[1] = cvtpk(st[2][2], st[2][3]);
        pf1.u[2] = cvtpk(st[3][0], st[3][1]);
        pf1.u[3] = cvtpk(st[3][2], st[3][3]);

        // ---- O^T += V^T P ; row-sum via MFMA-of-ones ----
        __builtin_amdgcn_s_setprio(1);
        lacc = __builtin_amdgcn_mfma_f32_16x16x32_bf16(ones, pf0.v, lacc, 0, 0, 0);
        lacc = __builtin_amdgcn_mfma_f32_16x16x32_bf16(ones, pf1.v, lacc, 0, 0, 0);
#pragma unroll
        for (int dc = 0; dc < 4; dc++) {
            o[dc] = __builtin_amdgcn_mfma_f32_16x16x32_bf16(av[dc][0], pf0.v, o[dc], 0, 0, 0);
            o[dc] = __builtin_amdgcn_mfma_f32_16x16x32_bf16(av[dc][1], pf1.v, o[dc], 0, 0, 0);
        }
        __builtin_amdgcn_s_setprio(0);

        __syncthreads();    // staged tile ready + all reads of buf[cur] done
        cur ^= 1;
    }

    // epilogue: lane holds o^T[d = dc*16 + lg*4 + jj][q = l15]
    const int b = bh >> 4, h = bh & 15;
    float inv = 1.f / lacc[0];
#pragma unroll
    for (int dc = 0; dc < 4; dc++) {
        ushort4 ov;
        ov.x = bf_bits(o[dc][0] * inv);
        ov.y = bf_bits(o[dc][1] * inv);
        ov.z = bf_bits(o[dc][2] * inv);
        ov.w = bf_bits(o[dc][3] * inv);
        *reinterpret_cast<ushort4*>(
            &y[(size_t)(b * T_SEQ + qr) * C_DIM + h * 64 + dc * 16 + lg * 4]) = ov;
    }
}

// ---------------- LayerNorm over C=1024 (bf16 in, f32 out), one block per row ----------------
__global__ __launch_bounds__(256) void ln_kernel(const __hip_bfloat16* __restrict__ y2,
                                                 const float* __restrict__ wgt,
                                                 const float* __restrict__ bias,
                                                 float* __restrict__ out) {
    const int row = blockIdx.x;
    const int t = threadIdx.x;
    ushort4 u = reinterpret_cast<const ushort4*>(y2 + (size_t)row * C_DIM)[t];
    float4 v;
    v.x = __bfloat162float(*(__hip_bfloat16*)&u.x);
    v.y = __bfloat162float(*(__hip_bfloat16*)&u.y);
    v.z = __bfloat162float(*(__hip_bfloat16*)&u.z);
    v.w = __bfloat162float(*(__hip_bfloat16*)&u.w);
    float s = v.x + v.y + v.z + v.w;
    float s2 = v.x * v.x + v.y * v.y + v.z * v.z + v.w * v.w;
#pragma unroll
    for (int d = 1; d < 64; d <<= 1) {
        s += __shfl_xor(s, d);
        s2 += __shfl_xor(s2, d);
    }
    __shared__ float ps[4], ps2[4];
    const int lane = t & 63, w = t >> 6;
    if (lane == 0) { ps[w] = s; ps2[w] = s2; }
    __syncthreads();
    s = ps[0] + ps[1] + ps[2] + ps[3];
    s2 = ps2[0] + ps2[1] + ps2[2] + ps2[3];
    float mean = s * (1.f / C_DIM);
    float var = s2 * (1.f / C_DIM) - mean * mean;
    float inv = rsqrtf(var + 1e-5f);
    float4 wv = reinterpret_cast<const float4*>(wgt)[t];
    float4 bv = reinterpret_cast<const float4*>(bias)[t];
    float4 ov;
    ov.x = (v.x - mean) * inv * wv.x + bv.x;
    ov.y = (v.y - mean) * inv * wv.y + bv.y;
    ov.z = (v.z - mean) * inv * wv.z + bv.z;
    ov.w = (v.w - mean) * inv * wv.w + bv.w;
    reinterpret_cast<float4*>(out + (size_t)row * C_DIM)[t] = ov;
}

extern "C" void kernel_launch(void* const* d_in, const int* in_sizes, int n_in,
                              void* d_out, int out_size, void* d_ws, size_t ws_size,
                              hipStream_t stream) {
    const float* x      = (const float*)d_in[0];
    const float* freqs  = (const float*)d_in[1];
    const float* W_attn = (const float*)d_in[2];
    const float* W_proj = (const float*)d_in[3];
    const float* lnw    = (const float*)d_in[4];
    const float* lnb    = (const float*)d_in[5];
    float* out = (float*)d_out;
    char* ws = (char*)d_ws;

    __hip_bfloat16* xb   = (__hip_bfloat16*)(ws);                 // 8.4 MB
    __hip_bfloat16* Wab  = (__hip_bfloat16*)(ws + 8388608);       // 6.3 MB
    __hip_bfloat16* Wpb  = (__hip_bfloat16*)(ws + 14680064);      // 2.1 MB
    __hip_bfloat16* qkvb = (__hip_bfloat16*)(ws + 16777216);      // 25.2 MB
    __hip_bfloat16* q_s  = (__hip_bfloat16*)(ws + 41943040);      // 8.4 MB
    __hip_bfloat16* k_s  = (__hip_bfloat16*)(ws + 50331648);      // 8.4 MB
    __hip_bfloat16* v_t  = (__hip_bfloat16*)(ws + 58720256);      // 8.4 MB (B,H,D,T)
    __hip_bfloat16* y_at = (__hip_bfloat16*)(ws + 67108864);      // 8.4 MB
    __hip_bfloat16* y2b  = (__hip_bfloat16*)(ws + 75497472);      // 8.4 MB

    // casts
    cast_f32_bf16<<<(BT * C_DIM / 4) / 256, 256, 0, stream>>>(x, xb, BT * C_DIM / 4);
    cast_f32_bf16<<<(C3 * C_DIM / 4) / 256, 256, 0, stream>>>(W_attn, Wab, C3 * C_DIM / 4);
    cast_f32_bf16<<<(C_DIM * C_DIM / 4) / 256, 256, 0, stream>>>(W_proj, Wpb, C_DIM * C_DIM / 4);

    // qkv = x @ W_attn^T
    gemm_bt<1><<<dim3(C3 / 128, BT / 128), 256, 0, stream>>>(xb, Wab, qkvb, BT, C3, C_DIM);

    // rope q,k + transpose v
    rope_qk<<<(BT * H_HEADS * 32) / 256, 256, 0, stream>>>(qkvb, freqs, q_s, k_s);
    transpose_v<<<dim3(T_SEQ / 64, BH), 256, 0, stream>>>(qkvb, v_t);

    // attention: 1024 blocks (32 q-tiles x 32 heads), LPT order
    attn_kernel<<<1024, 256, 0, stream>>>(q_s, k_s, v_t, y_at);

    // proj (bf16 out for cheap LN read)
    gemm_bt<1><<<dim3(C_DIM / 128, BT / 128), 256, 0, stream>>>(y_at, Wpb, y2b, BT, C_DIM, C_DIM);

    // layernorm
    ln_kernel<<<BT, 256, 0, stream>>>(y2b, lnw, lnb, out);
}

// Round 12
// 114.502 us; speedup vs baseline: 1.1229x; 1.0964x over previous
//
#include <hip/hip_runtime.h>
#include <hip/hip_bf16.h>
#include <math.h>

typedef short bf16x8 __attribute__((ext_vector_type(8)));
typedef float f32x4 __attribute__((ext_vector_type(4)));

#define T_SEQ 2048
#define C_DIM 1024
#define H_HEADS 16
#define D_HEAD 64
#define BT 4096          // B*T
#define C3 3072
#define BH 32            // B*H

static __device__ inline unsigned short bf_bits(float f) {
    __hip_bfloat16 h = __float2bfloat16(f);
    unsigned short u;
    __builtin_memcpy(&u, &h, 2);
    return u;
}

// packed f32x2 -> bf16x2 (RNE), single instruction
static __device__ inline unsigned int cvtpk(float lo, float hi) {
    unsigned int r;
    asm("v_cvt_pk_bf16_f32 %0, %1, %2" : "=v"(r) : "v"(lo), "v"(hi));
    return r;
}

__device__ __forceinline__ void gload16(const void* g, void* l) {
    __builtin_amdgcn_global_load_lds(
        (const __attribute__((address_space(1))) void*)g,
        (__attribute__((address_space(3))) void*)l, 16, 0, 0);
}

// LDS XOR swizzle (element units, 8-elem granule): spreads rows across bank quads
__device__ __forceinline__ int swz(int r) {
    return ((((r & 3) ^ ((r >> 3) & 3)) | (((r >> 3) & 1) << 2)) << 3);
}

// ---------------- cast f32 -> bf16, 4 elems/thread ----------------
__global__ void cast_f32_bf16(const float* __restrict__ in,
                              __hip_bfloat16* __restrict__ out, int n4) {
    int i = blockIdx.x * blockDim.x + threadIdx.x;
    if (i >= n4) return;
    float4 v = reinterpret_cast<const float4*>(in)[i];
    ushort4 o;
    o.x = bf_bits(v.x); o.y = bf_bits(v.y); o.z = bf_bits(v.z); o.w = bf_bits(v.w);
    reinterpret_cast<ushort4*>(out)[i] = o;
}

// ---------------- GEMM: Cout = A(M,K) * Bw(N,K)^T, bf16 MFMA ----------------
// 128xBN tile, BK=64, 4 waves. SINGLE-buffered m97 structure:
//   stage -> barrier (vmcnt drain) -> compute -> barrier
// Hiding comes from co-resident blocks (32KB LDS -> 3+ blocks/CU), which the
// 64KB double-buffer was throttling to 2 (and proj to 1). Swizzled source +
// XOR'd reads keep ds_read_b128 conflict-free.
template<int OUT_BF16, int BN>
__global__ __launch_bounds__(256) void gemm_bt(
    const __hip_bfloat16* __restrict__ A,
    const __hip_bfloat16* __restrict__ Bw,
    void* __restrict__ Cout, int M, int N, int K) {
    __shared__ __hip_bfloat16 As[128][64];
    __shared__ __hip_bfloat16 Bs[BN][64];
    const int t = threadIdx.x;
    const int lane = t & 63, w = t >> 6;
    const int wr = w >> 1, wc = w & 1;
    const int l15 = lane & 15, lg = lane >> 4;
    const int m0 = blockIdx.y * 128, n0 = blockIdx.x * BN;

    const int srow = lane >> 3;                   // 0..7 (row within 8-row stripe)
    const int scol = ((lane & 7) ^ srow) * 8;     // pre-swizzled global col granule
    const int xr = (l15 & 7) << 3;                // read-side XOR (element units)

    constexpr int NF = BN / 32;                   // n-fragments per wave
    f32x4 acc[4][NF];
    f32x4 zero4 = {0.f, 0.f, 0.f, 0.f};
#pragma unroll
    for (int m = 0; m < 4; m++)
#pragma unroll
        for (int n = 0; n < NF; n++) acc[m][n] = zero4;

    const int nt = K >> 6;
    for (int tk = 0; tk < nt; tk++) {
        const int k0 = tk << 6;
        // ---- stage tile (A: 128 rows, B: BN rows) ----
#pragma unroll
        for (int i = 0; i < 4; i++) {
            int rbase = w * 32 + i * 8;
            gload16(&A[(size_t)(m0 + rbase + srow) * K + k0 + scol], &As[rbase][0]);
        }
#pragma unroll
        for (int i = 0; i < NF; i++) {
            int rbase = w * (BN / 4) + i * 8;
            gload16(&Bw[(size_t)(n0 + rbase + srow) * K + k0 + scol], &Bs[rbase][0]);
        }
        __syncthreads();    // drains vmcnt(0): tile ready
#pragma unroll
        for (int kk = 0; kk < 2; kk++) {
            bf16x8 a[4], b[NF];
            const int co = (kk * 32 + lg * 8) ^ xr;
#pragma unroll
            for (int m = 0; m < 4; m++)
                a[m] = *reinterpret_cast<const bf16x8*>(&As[wr * 64 + m * 16 + l15][co]);
#pragma unroll
            for (int n = 0; n < NF; n++)
                b[n] = *reinterpret_cast<const bf16x8*>(&Bs[wc * (BN / 2) + n * 16 + l15][co]);
            __builtin_amdgcn_s_setprio(1);
#pragma unroll
            for (int m = 0; m < 4; m++)
#pragma unroll
                for (int n = 0; n < NF; n++)
                    acc[m][n] = __builtin_amdgcn_mfma_f32_16x16x32_bf16(a[m], b[n], acc[m][n], 0, 0, 0);
            __builtin_amdgcn_s_setprio(0);
        }
        __syncthreads();    // all reads done before next stage overwrites
    }

#pragma unroll
    for (int m = 0; m < 4; m++)
#pragma unroll
        for (int n = 0; n < NF; n++)
#pragma unroll
            for (int jj = 0; jj < 4; jj++) {
                int row = m0 + wr * 64 + m * 16 + lg * 4 + jj;
                int col = n0 + wc * (BN / 2) + n * 16 + l15;
                float v = acc[m][n][jj];
                if (OUT_BF16)
                    ((__hip_bfloat16*)Cout)[(size_t)row * N + col] = __float2bfloat16(v);
                else
                    ((float*)Cout)[(size_t)row * N + col] = v;
            }
}

// ---------------- RoPE for q,k -> (B,H,T,D); q pre-scaled by 0.125*log2(e) ----------------
__global__ void rope_qk(const __hip_bfloat16* __restrict__ qkv,
                        const float* __restrict__ freqs,
                        __hip_bfloat16* __restrict__ q_s,
                        __hip_bfloat16* __restrict__ k_s) {
    int idx = blockIdx.x * 256 + threadIdx.x;   // BT*H*32 threads
    int i = idx & 31;
    int h = (idx >> 5) & 15;
    int bt = idx >> 9;
    int b = bt >> 11;           // T=2048
    int tp = bt & 2047;
    float th = (float)tp * freqs[i];
    float sn = sinf(th), cs = cosf(th);
    size_t qoff = (size_t)bt * C3 + h * 64;
    float q1 = __bfloat162float(qkv[qoff + 2 * i]);
    float q2 = __bfloat162float(qkv[qoff + 2 * i + 1]);
    float k1 = __bfloat162float(qkv[qoff + C_DIM + 2 * i]);
    float k2 = __bfloat162float(qkv[qoff + C_DIM + 2 * i + 1]);
    size_t obase = ((size_t)(b * H_HEADS + h) * T_SEQ + tp) * D_HEAD;
    const float sc = 0.125f * 1.44269504f;      // 1/sqrt(D) * log2(e)
    q_s[obase + i]      = __float2bfloat16((q1 * cs - q2 * sn) * sc);
    q_s[obase + 32 + i] = __float2bfloat16((q1 * sn + q2 * cs) * sc);
    k_s[obase + i]      = __float2bfloat16(k1 * cs - k2 * sn);
    k_s[obase + 32 + i] = __float2bfloat16(k1 * sn + k2 * cs);
}

// ---------------- V transpose: qkv v-part -> v_t (B,H,D,T) ----------------
__global__ __launch_bounds__(256) void transpose_v(const __hip_bfloat16* __restrict__ qkv,
                                                   __hip_bfloat16* __restrict__ v_t) {
    __shared__ __hip_bfloat16 tile[64][72];
    const int bh = blockIdx.y, tt = blockIdx.x;
    const int b = bh >> 4, h = bh & 15;
    const int t = threadIdx.x;
    const int r = t >> 2, c0 = (t & 3) * 16;
    const __hip_bfloat16* src = qkv + (size_t)(b * T_SEQ + tt * 64 + r) * C3 + 2 * C_DIM + h * 64 + c0;
    uint4 v0 = reinterpret_cast<const uint4*>(src)[0];
    uint4 v1 = reinterpret_cast<const uint4*>(src)[1];
    *reinterpret_cast<uint4*>(&tile[r][c0]) = v0;
    *reinterpret_cast<uint4*>(&tile[r][c0 + 8]) = v1;
    __syncthreads();
    const int d = t >> 2;
    ushort out[16];
#pragma unroll
    for (int i = 0; i < 16; i++) {
        __hip_bfloat16 x = tile[c0 + i][d];
        __builtin_memcpy(&out[i], &x, 2);
    }
    __hip_bfloat16* dst = v_t + (size_t)bh * D_HEAD * T_SEQ + (size_t)d * T_SEQ + tt * 64 + c0;
    reinterpret_cast<uint4*>(dst)[0] = *reinterpret_cast<uint4*>(&out[0]);
    reinterpret_cast<uint4*>(dst)[1] = *reinterpret_cast<uint4*>(&out[8]);
}

// ---------------- flash attention ----------------
// Block = (head bh, 64-row q tile); 1024 blocks (4 blocks/CU), LPT order.
// Swapped QK^T, in-register P; K/V^T staged via global_load_lds, double-buffered;
// defer-max with shfl-free fast path; MFMA-of-ones row-sum; cvt_pk pack;
// builtin exp2.
__global__ __launch_bounds__(256, 4) void attn_kernel(
    const __hip_bfloat16* __restrict__ q_s,
    const __hip_bfloat16* __restrict__ k_s,
    const __hip_bfloat16* __restrict__ v_t,
    __hip_bfloat16* __restrict__ y) {
    __shared__ ushort Kbuf[2][64 * 64];
    __shared__ ushort Vbuf[2][64 * 64];

    const int bid = blockIdx.x;                 // 1024 blocks
    const int qt = 31 - (bid >> 5);             // LPT: longest first
    const int bh = bid & 31;                    // bh%8 -> head-per-XCD L2 locality
    const int t = threadIdx.x, lane = t & 63, w = t >> 6;
    const int l15 = lane & 15, lg = lane >> 4;
    const size_t hbase = (size_t)bh * T_SEQ * D_HEAD;
    const int qr = qt * 64 + w * 16 + l15;

    // Q fragment
    bf16x8 aq[2];
#pragma unroll
    for (int dd = 0; dd < 2; dd++)
        aq[dd] = *reinterpret_cast<const bf16x8*>(&q_s[hbase + (size_t)qr * 64 + dd * 32 + lg * 8]);

    // ones fragment (bf16 1.0 = 0x3F80) for MFMA row-sum
    bf16x8 ones;
#pragma unroll
    for (int i = 0; i < 8; i++) ones[i] = (short)0x3F80;

    f32x4 zero4 = {0.f, 0.f, 0.f, 0.f};
    f32x4 o[4];
#pragma unroll
    for (int dc = 0; dc < 4; dc++) o[dc] = zero4;
    f32x4 lacc = zero4;          // row-sum accumulator ([0] is the live value)
    float mr = -INFINITY;

    // LDS read offsets (element units), hoisted
    int koff[4][2], voff[4][2];
#pragma unroll
    for (int c = 0; c < 4; c++) {
        int kro = ((c >> 1) << 5) + ((c & 1) << 2) + ((l15 >> 2) << 3) + (l15 & 3);
        int sz = swz(kro);
#pragma unroll
        for (int dd = 0; dd < 2; dd++)
            koff[c][dd] = kro * 64 + ((dd * 32 + lg * 8) ^ sz);
    }
#pragma unroll
    for (int dc = 0; dc < 4; dc++) {
        int vro = dc * 16 + l15;
        int sz = swz(vro);
#pragma unroll
        for (int dd = 0; dd < 2; dd++)
            voff[dc][dd] = vro * 64 + ((dd * 32 + lg * 8) ^ sz);
    }

    // staging geometry: thread t -> tile row r_i = i*32 + (t>>3), granule t&7.
    const int srow = t >> 3;                // 0..31
    const int sgr = t & 7;

    auto stageKV = [&](int buf, int kbase) {
#pragma unroll
        for (int i = 0; i < 2; i++) {
            int r = i * 32 + srow;
            int gsw = (sgr ^ (swz(r) >> 3)) * 8;
            gload16(&k_s[hbase + (size_t)(kbase + r) * 64 + gsw],
                    &Kbuf[buf][(i * 32 + w * 8) * 64]);
            gload16(&v_t[hbase + (size_t)r * T_SEQ + kbase + gsw],
                    &Vbuf[buf][(i * 32 + w * 8) * 64]);
        }
    };

    int cur = 0;
    stageKV(0, 0);
    __syncthreads();        // drains vmcnt: buf0 ready

    for (int kt = 0; kt <= qt; kt++) {
        const int kt64 = kt << 6;
        if (kt < qt) stageKV(cur ^ 1, kt64 + 64);   // in flight during compute

        const ushort* Kc = Kbuf[cur];
        const ushort* Vc = Vbuf[cur];
        bf16x8 kf[4][2], av[4][2];
#pragma unroll
        for (int c = 0; c < 4; c++)
#pragma unroll
            for (int dd = 0; dd < 2; dd++)
                kf[c][dd] = *reinterpret_cast<const bf16x8*>(&Kc[koff[c][dd]]);
#pragma unroll
        for (int dc = 0; dc < 4; dc++)
#pragma unroll
            for (int dd = 0; dd < 2; dd++)
                av[dc][dd] = *reinterpret_cast<const bf16x8*>(&Vc[voff[dc][dd]]);

        // ---- S^T = K * Q^T ----
        f32x4 st[4];
        __builtin_amdgcn_s_setprio(1);
#pragma unroll
        for (int c = 0; c < 4; c++) {
            st[c] = zero4;
#pragma unroll
            for (int dd = 0; dd < 2; dd++)
                st[c] = __builtin_amdgcn_mfma_f32_16x16x32_bf16(kf[c][dd], aq[dd], st[c], 0, 0, 0);
        }
        __builtin_amdgcn_s_setprio(0);

        if (kt == qt) {     // causal mask on diagonal tile
#pragma unroll
            for (int c = 0; c < 4; c++) {
                int kb = kt64 + ((c >> 1) << 5) + ((c & 1) << 2) + lg * 8;
#pragma unroll
                for (int jj = 0; jj < 4; jj++)
                    if (kb + jj > qr) st[c][jj] = -INFINITY;
            }
        }

        // ---- per-lane LOCAL max (no cross-lane shuffles on the fast path) ----
        float m0a = fmaxf(st[0][0], st[0][1]), m0b = fmaxf(st[0][2], st[0][3]);
        float m1a = fmaxf(st[1][0], st[1][1]), m1b = fmaxf(st[1][2], st[1][3]);
        float m2a = fmaxf(st[2][0], st[2][1]), m2b = fmaxf(st[2][2], st[2][3]);
        float m3a = fmaxf(st[3][0], st[3][1]), m3b = fmaxf(st[3][2], st[3][3]);
        float lmx = fmaxf(fmaxf(fmaxf(m0a, m0b), fmaxf(m1a, m1b)),
                          fmaxf(fmaxf(m2a, m2b), fmaxf(m3a, m3b)));

        // ---- defer-max: rescale only when some lane's local max grew past THR=8 ----
        if (__any(lmx - mr > 8.f)) {
            float mx = fmaxf(lmx, __shfl_xor(lmx, 16));
            mx = fmaxf(mx, __shfl_xor(mx, 32));
            float mnew = fmaxf(mr, mx);
            float scl = __builtin_amdgcn_exp2f(mr - mnew);
            mr = mnew;
            lacc[0] *= scl;
#pragma unroll
            for (int dc = 0; dc < 4; dc++)
#pragma unroll
                for (int jj = 0; jj < 4; jj++) o[dc][jj] *= scl;
        }

        // ---- P = exp2(S - mr) (bare v_exp_f32), pack to bf16 (cvt_pk) ----
#pragma unroll
        for (int c = 0; c < 4; c++)
#pragma unroll
            for (int jj = 0; jj < 4; jj++)
                st[c][jj] = __builtin_amdgcn_exp2f(st[c][jj] - mr);

        union { bf16x8 v; unsigned int u[4]; } pf0, pf1;
        pf0.u[0] = cvtpk(st[0][0], st[0][1]);
        pf0.u[1] = cvtpk(st[0][2], st[0][3]);
        pf0.u[2] = cvtpk(st[1][0], st[1][1]);
        pf0.u[3] = cvtpk(st[1][2], st[1][3]);
        pf1.u[0] = cvtpk(st[2][0], st[2][1]);
        pf1.u[1] = cvtpk(st[2][2], st[2][3]);
        pf1.u[2] = cvtpk(st[3][0], st[3][1]);
        pf1.u[3] = cvtpk(st[3][2], st[3][3]);

        // ---- O^T += V^T P ; row-sum via MFMA-of-ones ----
        __builtin_amdgcn_s_setprio(1);
        lacc = __builtin_amdgcn_mfma_f32_16x16x32_bf16(ones, pf0.v, lacc, 0, 0, 0);
        lacc = __builtin_amdgcn_mfma_f32_16x16x32_bf16(ones, pf1.v, lacc, 0, 0, 0);
#pragma unroll
        for (int dc = 0; dc < 4; dc++) {
            o[dc] = __builtin_amdgcn_mfma_f32_16x16x32_bf16(av[dc][0], pf0.v, o[dc], 0, 0, 0);
            o[dc] = __builtin_amdgcn_mfma_f32_16x16x32_bf16(av[dc][1], pf1.v, o[dc], 0, 0, 0);
        }
        __builtin_amdgcn_s_setprio(0);

        __syncthreads();    // staged tile ready + all reads of buf[cur] done
        cur ^= 1;
    }

    // epilogue: lane holds o^T[d = dc*16 + lg*4 + jj][q = l15]
    const int b = bh >> 4, h = bh & 15;
    float inv = 1.f / lacc[0];
#pragma unroll
    for (int dc = 0; dc < 4; dc++) {
        ushort4 ov;
        ov.x = bf_bits(o[dc][0] * inv);
        ov.y = bf_bits(o[dc][1] * inv);
        ov.z = bf_bits(o[dc][2] * inv);
        ov.w = bf_bits(o[dc][3] * inv);
        *reinterpret_cast<ushort4*>(
            &y[(size_t)(b * T_SEQ + qr) * C_DIM + h * 64 + dc * 16 + lg * 4]) = ov;
    }
}

// ---------------- LayerNorm over C=1024 (bf16 in, f32 out), one block per row ----------------
__global__ __launch_bounds__(256) void ln_kernel(const __hip_bfloat16* __restrict__ y2,
                                                 const float* __restrict__ wgt,
                                                 const float* __restrict__ bias,
                                                 float* __restrict__ out) {
    const int row = blockIdx.x;
    const int t = threadIdx.x;
    ushort4 u = reinterpret_cast<const ushort4*>(y2 + (size_t)row * C_DIM)[t];
    float4 v;
    v.x = __bfloat162float(*(__hip_bfloat16*)&u.x);
    v.y = __bfloat162float(*(__hip_bfloat16*)&u.y);
    v.z = __bfloat162float(*(__hip_bfloat16*)&u.z);
    v.w = __bfloat162float(*(__hip_bfloat16*)&u.w);
    float s = v.x + v.y + v.z + v.w;
    float s2 = v.x * v.x + v.y * v.y + v.z * v.z + v.w * v.w;
#pragma unroll
    for (int d = 1; d < 64; d <<= 1) {
        s += __shfl_xor(s, d);
        s2 += __shfl_xor(s2, d);
    }
    __shared__ float ps[4], ps2[4];
    const int lane = t & 63, w = t >> 6;
    if (lane == 0) { ps[w] = s; ps2[w] = s2; }
    __syncthreads();
    s = ps[0] + ps[1] + ps[2] + ps[3];
    s2 = ps2[0] + ps2[1] + ps2[2] + ps2[3];
    float mean = s * (1.f / C_DIM);
    float var = s2 * (1.f / C_DIM) - mean * mean;
    float inv = rsqrtf(var + 1e-5f);
    float4 wv = reinterpret_cast<const float4*>(wgt)[t];
    float4 bv = reinterpret_cast<const float4*>(bias)[t];
    float4 ov;
    ov.x = (v.x - mean) * inv * wv.x + bv.x;
    ov.y = (v.y - mean) * inv * wv.y + bv.y;
    ov.z = (v.z - mean) * inv * wv.z + bv.z;
    ov.w = (v.w - mean) * inv * wv.w + bv.w;
    reinterpret_cast<float4*>(out + (size_t)row * C_DIM)[t] = ov;
}

extern "C" void kernel_launch(void* const* d_in, const int* in_sizes, int n_in,
                              void* d_out, int out_size, void* d_ws, size_t ws_size,
                              hipStream_t stream) {
    const float* x      = (const float*)d_in[0];
    const float* freqs  = (const float*)d_in[1];
    const float* W_attn = (const float*)d_in[2];
    const float* W_proj = (const float*)d_in[3];
    const float* lnw    = (const float*)d_in[4];
    const float* lnb    = (const float*)d_in[5];
    float* out = (float*)d_out;
    char* ws = (char*)d_ws;

    __hip_bfloat16* xb   = (__hip_bfloat16*)(ws);                 // 8.4 MB
    __hip_bfloat16* Wab  = (__hip_bfloat16*)(ws + 8388608);       // 6.3 MB
    __hip_bfloat16* Wpb  = (__hip_bfloat16*)(ws + 14680064);      // 2.1 MB
    __hip_bfloat16* qkvb = (__hip_bfloat16*)(ws + 16777216);      // 25.2 MB
    __hip_bfloat16* q_s  = (__hip_bfloat16*)(ws + 41943040);      // 8.4 MB
    __hip_bfloat16* k_s  = (__hip_bfloat16*)(ws + 50331648);      // 8.4 MB
    __hip_bfloat16* v_t  = (__hip_bfloat16*)(ws + 58720256);      // 8.4 MB (B,H,D,T)
    __hip_bfloat16* y_at = (__hip_bfloat16*)(ws + 67108864);      // 8.4 MB
    __hip_bfloat16* y2b  = (__hip_bfloat16*)(ws + 75497472);      // 8.4 MB

    // casts
    cast_f32_bf16<<<(BT * C_DIM / 4) / 256, 256, 0, stream>>>(x, xb, BT * C_DIM / 4);
    cast_f32_bf16<<<(C3 * C_DIM / 4) / 256, 256, 0, stream>>>(W_attn, Wab, C3 * C_DIM / 4);
    cast_f32_bf16<<<(C_DIM * C_DIM / 4) / 256, 256, 0, stream>>>(W_proj, Wpb, C_DIM * C_DIM / 4);

    // qkv = x @ W_attn^T  (128x128 tile, 768 blocks = 3/CU exactly)
    gemm_bt<1, 128><<<dim3(C3 / 128, BT / 128), 256, 0, stream>>>(xb, Wab, qkvb, BT, C3, C_DIM);

    // rope q,k + transpose v
    rope_qk<<<(BT * H_HEADS * 32) / 256, 256, 0, stream>>>(qkvb, freqs, q_s, k_s);
    transpose_v<<<dim3(T_SEQ / 64, BH), 256, 0, stream>>>(qkvb, v_t);

    // attention: 1024 blocks (32 q-tiles x 32 heads), LPT order
    attn_kernel<<<1024, 256, 0, stream>>>(q_s, k_s, v_t, y_at);

    // proj (128x64 tile, 512 blocks = 2/CU exactly; bf16 out for cheap LN read)
    gemm_bt<1, 64><<<dim3(C_DIM / 64, BT / 128), 256, 0, stream>>>(y_at, Wpb, y2b, BT, C_DIM, C_DIM);

    // layernorm
    ln_kernel<<<BT, 256, 0, stream>>>(y2b, lnw, lnb, out);
}

// Round 13
// 112.494 us; speedup vs baseline: 1.1429x; 1.0179x over previous
//
#include <hip/hip_runtime.h>
#include <hip/hip_bf16.h>
#include <math.h>

typedef short bf16x8 __attribute__((ext_vector_type(8)));
typedef float f32x4 __attribute__((ext_vector_type(4)));

#define T_SEQ 2048
#define C_DIM 1024
#define H_HEADS 16
#define D_HEAD 64
#define BT 4096          // B*T
#define C3 3072
#define BH 32            // B*H

static __device__ inline unsigned short bf_bits(float f) {
    __hip_bfloat16 h = __float2bfloat16(f);
    unsigned short u;
    __builtin_memcpy(&u, &h, 2);
    return u;
}

// packed f32x2 -> bf16x2 (RNE), single instruction
static __device__ inline unsigned int cvtpk(float lo, float hi) {
    unsigned int r;
    asm("v_cvt_pk_bf16_f32 %0, %1, %2" : "=v"(r) : "v"(lo), "v"(hi));
    return r;
}

__device__ __forceinline__ void gload16(const void* g, void* l) {
    __builtin_amdgcn_global_load_lds(
        (const __attribute__((address_space(1))) void*)g,
        (__attribute__((address_space(3))) void*)l, 16, 0, 0);
}

// LDS XOR swizzle (element units, 8-elem granule): spreads rows across bank quads
__device__ __forceinline__ int swz(int r) {
    return ((((r & 3) ^ ((r >> 3) & 3)) | (((r >> 3) & 1) << 2)) << 3);
}

// ---------------- cast f32 -> bf16, 4 elems/thread ----------------
__global__ void cast_f32_bf16(const float* __restrict__ in,
                              __hip_bfloat16* __restrict__ out, int n4) {
    int i = blockIdx.x * blockDim.x + threadIdx.x;
    if (i >= n4) return;
    float4 v = reinterpret_cast<const float4*>(in)[i];
    ushort4 o;
    o.x = bf_bits(v.x); o.y = bf_bits(v.y); o.z = bf_bits(v.z); o.w = bf_bits(v.w);
    reinterpret_cast<ushort4*>(out)[i] = o;
}

// ---------------- RoPE cos/sin table: tab[t][i] = (cos, sin), T x 32 ----------------
__global__ void rope_table(const float* __restrict__ freqs, float2* __restrict__ tab) {
    int idx = blockIdx.x * 256 + threadIdx.x;   // T_SEQ*32 threads
    int i = idx & 31, tp = idx >> 5;
    float th = (float)tp * freqs[i];
    tab[idx] = make_float2(cosf(th), sinf(th));
}

// ---------------- GEMM: A(M,K) * Bw(N,K)^T, bf16 MFMA ----------------
// 128xBN tile, BK=64, 4 waves. Single-buffered m97 structure (residency-optimal).
// MODE 0: f32 C row-major. MODE 1: bf16 C row-major.
// MODE 2 (qkv fused epilogue): region = n0>>10 (block-uniform):
//   q (0): RoPE + 0.125*log2e scale -> q_s (B,H,T,D)
//   k (1): RoPE                      -> k_s (B,H,T,D)
//   v (2): transpose store           -> v_t (B,H,D,T)  [ushort4 over 4 t's]
// RoPE pairing (2i,2i+1) lives in ADJACENT LANES (col = ..+l15) -> one shfl_xor(1).
template<int MODE, int BN>
__global__ __launch_bounds__(256) void gemm_bt(
    const __hip_bfloat16* __restrict__ A,
    const __hip_bfloat16* __restrict__ Bw,
    void* __restrict__ Cout, int M, int N, int K,
    const float2* __restrict__ tab,
    __hip_bfloat16* __restrict__ q_s,
    __hip_bfloat16* __restrict__ k_s,
    __hip_bfloat16* __restrict__ v_t) {
    __shared__ __hip_bfloat16 As[128][64];
    __shared__ __hip_bfloat16 Bs[BN][64];
    const int t = threadIdx.x;
    const int lane = t & 63, w = t >> 6;
    const int wr = w >> 1, wc = w & 1;
    const int l15 = lane & 15, lg = lane >> 4;
    const int m0 = blockIdx.y * 128, n0 = blockIdx.x * BN;

    const int srow = lane >> 3;                   // 0..7 (row within 8-row stripe)
    const int scol = ((lane & 7) ^ srow) * 8;     // pre-swizzled global col granule
    const int xr = (l15 & 7) << 3;                // read-side XOR (element units)

    constexpr int NF = BN / 32;                   // n-fragments per wave
    f32x4 acc[4][NF];
    f32x4 zero4 = {0.f, 0.f, 0.f, 0.f};
#pragma unroll
    for (int m = 0; m < 4; m++)
#pragma unroll
        for (int n = 0; n < NF; n++) acc[m][n] = zero4;

    const int nt = K >> 6;
    for (int tk = 0; tk < nt; tk++) {
        const int k0 = tk << 6;
#pragma unroll
        for (int i = 0; i < 4; i++) {
            int rbase = w * 32 + i * 8;
            gload16(&A[(size_t)(m0 + rbase + srow) * K + k0 + scol], &As[rbase][0]);
        }
#pragma unroll
        for (int i = 0; i < NF; i++) {
            int rbase = w * (BN / 4) + i * 8;
            gload16(&Bw[(size_t)(n0 + rbase + srow) * K + k0 + scol], &Bs[rbase][0]);
        }
        __syncthreads();    // drains vmcnt(0): tile ready
#pragma unroll
        for (int kk = 0; kk < 2; kk++) {
            bf16x8 a[4], b[NF];
            const int co = (kk * 32 + lg * 8) ^ xr;
#pragma unroll
            for (int m = 0; m < 4; m++)
                a[m] = *reinterpret_cast<const bf16x8*>(&As[wr * 64 + m * 16 + l15][co]);
#pragma unroll
            for (int n = 0; n < NF; n++)
                b[n] = *reinterpret_cast<const bf16x8*>(&Bs[wc * (BN / 2) + n * 16 + l15][co]);
            __builtin_amdgcn_s_setprio(1);
#pragma unroll
            for (int m = 0; m < 4; m++)
#pragma unroll
                for (int n = 0; n < NF; n++)
                    acc[m][n] = __builtin_amdgcn_mfma_f32_16x16x32_bf16(a[m], b[n], acc[m][n], 0, 0, 0);
            __builtin_amdgcn_s_setprio(0);
        }
        __syncthreads();    // all reads done before next stage overwrites
    }

    if (MODE == 2) {
        const int region = n0 >> 10;            // 0=q, 1=k, 2=v (block-uniform)
#pragma unroll
        for (int m = 0; m < 4; m++)
#pragma unroll
            for (int n = 0; n < NF; n++) {
                const int col = n0 + wc * (BN / 2) + n * 16 + l15;
                const int d = col & 63;
                const int h = (col >> 6) & 15;
                const int row0 = m0 + wr * 64 + m * 16 + lg * 4;
                const int b = row0 >> 11;       // 4 consecutive rows share b (2048|128)
                const int tp0 = row0 & 2047;
                if (region < 2) {
                    const int i = d >> 1, odd = d & 1;
                    const int dp = (d >> 1) + (odd ? 32 : 0);
                    __hip_bfloat16* dst = (region == 0) ? q_s : k_s;
                    const float sc = (region == 0) ? 0.125f * 1.44269504f : 1.0f;
#pragma unroll
                    for (int jj = 0; jj < 4; jj++) {
                        float own = acc[m][n][jj];
                        float par = __shfl_xor(own, 1);
                        float2 cs = tab[(tp0 + jj) * 32 + i];
                        float val = own * cs.x + (odd ? par : -par) * cs.y;
                        dst[((size_t)(b * H_HEADS + h) * T_SEQ + tp0 + jj) * D_HEAD + dp] =
                            __float2bfloat16(val * sc);
                    }
                } else {
                    ushort4 ov;
                    ov.x = bf_bits(acc[m][n][0]);
                    ov.y = bf_bits(acc[m][n][1]);
                    ov.z = bf_bits(acc[m][n][2]);
                    ov.w = bf_bits(acc[m][n][3]);
                    *reinterpret_cast<ushort4*>(
                        &v_t[((size_t)(b * H_HEADS + h) * D_HEAD + d) * T_SEQ + tp0]) = ov;
                }
            }
        return;
    }

#pragma unroll
    for (int m = 0; m < 4; m++)
#pragma unroll
        for (int n = 0; n < NF; n++)
#pragma unroll
            for (int jj = 0; jj < 4; jj++) {
                int row = m0 + wr * 64 + m * 16 + lg * 4 + jj;
                int col = n0 + wc * (BN / 2) + n * 16 + l15;
                float v = acc[m][n][jj];
                if (MODE == 1)
                    ((__hip_bfloat16*)Cout)[(size_t)row * N + col] = __float2bfloat16(v);
                else
                    ((float*)Cout)[(size_t)row * N + col] = v;
            }
}

// ---------------- flash attention ----------------
// Block = (head bh, 64-row q tile); 1024 blocks (4 blocks/CU), LPT order.
// Swapped QK^T, in-register P; K/V^T staged via global_load_lds, double-buffered;
// defer-max with shfl-free fast path; MFMA-of-ones row-sum; cvt_pk pack;
// builtin exp2.
__global__ __launch_bounds__(256, 4) void attn_kernel(
    const __hip_bfloat16* __restrict__ q_s,
    const __hip_bfloat16* __restrict__ k_s,
    const __hip_bfloat16* __restrict__ v_t,
    __hip_bfloat16* __restrict__ y) {
    __shared__ ushort Kbuf[2][64 * 64];
    __shared__ ushort Vbuf[2][64 * 64];

    const int bid = blockIdx.x;                 // 1024 blocks
    const int qt = 31 - (bid >> 5);             // LPT: longest first
    const int bh = bid & 31;                    // bh%8 -> head-per-XCD L2 locality
    const int t = threadIdx.x, lane = t & 63, w = t >> 6;
    const int l15 = lane & 15, lg = lane >> 4;
    const size_t hbase = (size_t)bh * T_SEQ * D_HEAD;
    const int qr = qt * 64 + w * 16 + l15;

    // Q fragment
    bf16x8 aq[2];
#pragma unroll
    for (int dd = 0; dd < 2; dd++)
        aq[dd] = *reinterpret_cast<const bf16x8*>(&q_s[hbase + (size_t)qr * 64 + dd * 32 + lg * 8]);

    // ones fragment (bf16 1.0 = 0x3F80) for MFMA row-sum
    bf16x8 ones;
#pragma unroll
    for (int i = 0; i < 8; i++) ones[i] = (short)0x3F80;

    f32x4 zero4 = {0.f, 0.f, 0.f, 0.f};
    f32x4 o[4];
#pragma unroll
    for (int dc = 0; dc < 4; dc++) o[dc] = zero4;
    f32x4 lacc = zero4;          // row-sum accumulator ([0] is the live value)
    float mr = -INFINITY;

    // LDS read offsets (element units), hoisted
    int koff[4][2], voff[4][2];
#pragma unroll
    for (int c = 0; c < 4; c++) {
        int kro = ((c >> 1) << 5) + ((c & 1) << 2) + ((l15 >> 2) << 3) + (l15 & 3);
        int sz = swz(kro);
#pragma unroll
        for (int dd = 0; dd < 2; dd++)
            koff[c][dd] = kro * 64 + ((dd * 32 + lg * 8) ^ sz);
    }
#pragma unroll
    for (int dc = 0; dc < 4; dc++) {
        int vro = dc * 16 + l15;
        int sz = swz(vro);
#pragma unroll
        for (int dd = 0; dd < 2; dd++)
            voff[dc][dd] = vro * 64 + ((dd * 32 + lg * 8) ^ sz);
    }

    // staging geometry: thread t -> tile row r_i = i*32 + (t>>3), granule t&7.
    const int srow = t >> 3;                // 0..31
    const int sgr = t & 7;

    auto stageKV = [&](int buf, int kbase) {
#pragma unroll
        for (int i = 0; i < 2; i++) {
            int r = i * 32 + srow;
            int gsw = (sgr ^ (swz(r) >> 3)) * 8;
            gload16(&k_s[hbase + (size_t)(kbase + r) * 64 + gsw],
                    &Kbuf[buf][(i * 32 + w * 8) * 64]);
            gload16(&v_t[hbase + (size_t)r * T_SEQ + kbase + gsw],
                    &Vbuf[buf][(i * 32 + w * 8) * 64]);
        }
    };

    int cur = 0;
    stageKV(0, 0);
    __syncthreads();        // drains vmcnt: buf0 ready

    for (int kt = 0; kt <= qt; kt++) {
        const int kt64 = kt << 6;
        if (kt < qt) stageKV(cur ^ 1, kt64 + 64);   // in flight during compute

        const ushort* Kc = Kbuf[cur];
        const ushort* Vc = Vbuf[cur];
        bf16x8 kf[4][2], av[4][2];
#pragma unroll
        for (int c = 0; c < 4; c++)
#pragma unroll
            for (int dd = 0; dd < 2; dd++)
                kf[c][dd] = *reinterpret_cast<const bf16x8*>(&Kc[koff[c][dd]]);
#pragma unroll
        for (int dc = 0; dc < 4; dc++)
#pragma unroll
            for (int dd = 0; dd < 2; dd++)
                av[dc][dd] = *reinterpret_cast<const bf16x8*>(&Vc[voff[dc][dd]]);

        // ---- S^T = K * Q^T ----
        f32x4 st[4];
        __builtin_amdgcn_s_setprio(1);
#pragma unroll
        for (int c = 0; c < 4; c++) {
            st[c] = zero4;
#pragma unroll
            for (int dd = 0; dd < 2; dd++)
                st[c] = __builtin_amdgcn_mfma_f32_16x16x32_bf16(kf[c][dd], aq[dd], st[c], 0, 0, 0);
        }
        __builtin_amdgcn_s_setprio(0);

        if (kt == qt) {     // causal mask on diagonal tile
#pragma unroll
            for (int c = 0; c < 4; c++) {
                int kb = kt64 + ((c >> 1) << 5) + ((c & 1) << 2) + lg * 8;
#pragma unroll
                for (int jj = 0; jj < 4; jj++)
                    if (kb + jj > qr) st[c][jj] = -INFINITY;
            }
        }

        // ---- per-lane LOCAL max (no cross-lane shuffles on the fast path) ----
        float m0a = fmaxf(st[0][0], st[0][1]), m0b = fmaxf(st[0][2], st[0][3]);
        float m1a = fmaxf(st[1][0], st[1][1]), m1b = fmaxf(st[1][2], st[1][3]);
        float m2a = fmaxf(st[2][0], st[2][1]), m2b = fmaxf(st[2][2], st[2][3]);
        float m3a = fmaxf(st[3][0], st[3][1]), m3b = fmaxf(st[3][2], st[3][3]);
        float lmx = fmaxf(fmaxf(fmaxf(m0a, m0b), fmaxf(m1a, m1b)),
                          fmaxf(fmaxf(m2a, m2b), fmaxf(m3a, m3b)));

        // ---- defer-max: rescale only when some lane's local max grew past THR=8 ----
        if (__any(lmx - mr > 8.f)) {
            float mx = fmaxf(lmx, __shfl_xor(lmx, 16));
            mx = fmaxf(mx, __shfl_xor(mx, 32));
            float mnew = fmaxf(mr, mx);
            float scl = __builtin_amdgcn_exp2f(mr - mnew);
            mr = mnew;
            lacc[0] *= scl;
#pragma unroll
            for (int dc = 0; dc < 4; dc++)
#pragma unroll
                for (int jj = 0; jj < 4; jj++) o[dc][jj] *= scl;
        }

        // ---- P = exp2(S - mr) (bare v_exp_f32), pack to bf16 (cvt_pk) ----
#pragma unroll
        for (int c = 0; c < 4; c++)
#pragma unroll
            for (int jj = 0; jj < 4; jj++)
                st[c][jj] = __builtin_amdgcn_exp2f(st[c][jj] - mr);

        union { bf16x8 v; unsigned int u[4]; } pf0, pf1;
        pf0.u[0] = cvtpk(st[0][0], st[0][1]);
        pf0.u[1] = cvtpk(st[0][2], st[0][3]);
        pf0.u[2] = cvtpk(st[1][0], st[1][1]);
        pf0.u[3] = cvtpk(st[1][2], st[1][3]);
        pf1.u[0] = cvtpk(st[2][0], st[2][1]);
        pf1.u[1] = cvtpk(st[2][2], st[2][3]);
        pf1.u[2] = cvtpk(st[3][0], st[3][1]);
        pf1.u[3] = cvtpk(st[3][2], st[3][3]);

        // ---- O^T += V^T P ; row-sum via MFMA-of-ones ----
        __builtin_amdgcn_s_setprio(1);
        lacc = __builtin_amdgcn_mfma_f32_16x16x32_bf16(ones, pf0.v, lacc, 0, 0, 0);
        lacc = __builtin_amdgcn_mfma_f32_16x16x32_bf16(ones, pf1.v, lacc, 0, 0, 0);
#pragma unroll
        for (int dc = 0; dc < 4; dc++) {
            o[dc] = __builtin_amdgcn_mfma_f32_16x16x32_bf16(av[dc][0], pf0.v, o[dc], 0, 0, 0);
            o[dc] = __builtin_amdgcn_mfma_f32_16x16x32_bf16(av[dc][1], pf1.v, o[dc], 0, 0, 0);
        }
        __builtin_amdgcn_s_setprio(0);

        __syncthreads();    // staged tile ready + all reads of buf[cur] done
        cur ^= 1;
    }

    // epilogue: lane holds o^T[d = dc*16 + lg*4 + jj][q = l15]
    const int b = bh >> 4, h = bh & 15;
    float inv = 1.f / lacc[0];
#pragma unroll
    for (int dc = 0; dc < 4; dc++) {
        ushort4 ov;
        ov.x = bf_bits(o[dc][0] * inv);
        ov.y = bf_bits(o[dc][1] * inv);
        ov.z = bf_bits(o[dc][2] * inv);
        ov.w = bf_bits(o[dc][3] * inv);
        *reinterpret_cast<ushort4*>(
            &y[(size_t)(b * T_SEQ + qr) * C_DIM + h * 64 + dc * 16 + lg * 4]) = ov;
    }
}

// ---------------- LayerNorm over C=1024 (bf16 in, f32 out), one block per row ----------------
__global__ __launch_bounds__(256) void ln_kernel(const __hip_bfloat16* __restrict__ y2,
                                                 const float* __restrict__ wgt,
                                                 const float* __restrict__ bias,
                                                 float* __restrict__ out) {
    const int row = blockIdx.x;
    const int t = threadIdx.x;
    ushort4 u = reinterpret_cast<const ushort4*>(y2 + (size_t)row * C_DIM)[t];
    float4 v;
    v.x = __bfloat162float(*(__hip_bfloat16*)&u.x);
    v.y = __bfloat162float(*(__hip_bfloat16*)&u.y);
    v.z = __bfloat162float(*(__hip_bfloat16*)&u.z);
    v.w = __bfloat162float(*(__hip_bfloat16*)&u.w);
    float s = v.x + v.y + v.z + v.w;
    float s2 = v.x * v.x + v.y * v.y + v.z * v.z + v.w * v.w;
#pragma unroll
    for (int d = 1; d < 64; d <<= 1) {
        s += __shfl_xor(s, d);
        s2 += __shfl_xor(s2, d);
    }
    __shared__ float ps[4], ps2[4];
    const int lane = t & 63, w = t >> 6;
    if (lane == 0) { ps[w] = s; ps2[w] = s2; }
    __syncthreads();
    s = ps[0] + ps[1] + ps[2] + ps[3];
    s2 = ps2[0] + ps2[1] + ps2[2] + ps2[3];
    float mean = s * (1.f / C_DIM);
    float var = s2 * (1.f / C_DIM) - mean * mean;
    float inv = rsqrtf(var + 1e-5f);
    float4 wv = reinterpret_cast<const float4*>(wgt)[t];
    float4 bv = reinterpret_cast<const float4*>(bias)[t];
    float4 ov;
    ov.x = (v.x - mean) * inv * wv.x + bv.x;
    ov.y = (v.y - mean) * inv * wv.y + bv.y;
    ov.z = (v.z - mean) * inv * wv.z + bv.z;
    ov.w = (v.w - mean) * inv * wv.w + bv.w;
    reinterpret_cast<float4*>(out + (size_t)row * C_DIM)[t] = ov;
}

extern "C" void kernel_launch(void* const* d_in, const int* in_sizes, int n_in,
                              void* d_out, int out_size, void* d_ws, size_t ws_size,
                              hipStream_t stream) {
    const float* x      = (const float*)d_in[0];
    const float* freqs  = (const float*)d_in[1];
    const float* W_attn = (const float*)d_in[2];
    const float* W_proj = (const float*)d_in[3];
    const float* lnw    = (const float*)d_in[4];
    const float* lnb    = (const float*)d_in[5];
    float* out = (float*)d_out;
    char* ws = (char*)d_ws;

    __hip_bfloat16* xb   = (__hip_bfloat16*)(ws);                 // 8.4 MB
    __hip_bfloat16* Wab  = (__hip_bfloat16*)(ws + 8388608);       // 6.3 MB
    __hip_bfloat16* Wpb  = (__hip_bfloat16*)(ws + 14680064);      // 2.1 MB
    float2*         tab  = (float2*)(ws + 16777216);              // 512 KB cos/sin table
    __hip_bfloat16* q_s  = (__hip_bfloat16*)(ws + 41943040);      // 8.4 MB
    __hip_bfloat16* k_s  = (__hip_bfloat16*)(ws + 50331648);      // 8.4 MB
    __hip_bfloat16* v_t  = (__hip_bfloat16*)(ws + 58720256);      // 8.4 MB (B,H,D,T)
    __hip_bfloat16* y_at = (__hip_bfloat16*)(ws + 67108864);      // 8.4 MB
    __hip_bfloat16* y2b  = (__hip_bfloat16*)(ws + 75497472);      // 8.4 MB

    // cos/sin table + casts
    rope_table<<<(T_SEQ * 32) / 256, 256, 0, stream>>>(freqs, tab);
    cast_f32_bf16<<<(BT * C_DIM / 4) / 256, 256, 0, stream>>>(x, xb, BT * C_DIM / 4);
    cast_f32_bf16<<<(C3 * C_DIM / 4) / 256, 256, 0, stream>>>(W_attn, Wab, C3 * C_DIM / 4);
    cast_f32_bf16<<<(C_DIM * C_DIM / 4) / 256, 256, 0, stream>>>(W_proj, Wpb, C_DIM * C_DIM / 4);

    // qkv GEMM with fused RoPE/scatter epilogue (no qkv intermediate buffer)
    gemm_bt<2, 128><<<dim3(C3 / 128, BT / 128), 256, 0, stream>>>(
        xb, Wab, nullptr, BT, C3, C_DIM, tab, q_s, k_s, v_t);

    // attention: 1024 blocks (32 q-tiles x 32 heads), LPT order
    attn_kernel<<<1024, 256, 0, stream>>>(q_s, k_s, v_t, y_at);

    // proj (128x64 tile, 512 blocks = 2/CU exactly; bf16 out for cheap LN read)
    gemm_bt<1, 64><<<dim3(C_DIM / 64, BT / 128), 256, 0, stream>>>(
        y_at, Wpb, y2b, BT, C_DIM, C_DIM, nullptr, nullptr, nullptr, nullptr);

    // layernorm
    ln_kernel<<<BT, 256, 0, stream>>>(y2b, lnw, lnb, out);
}